// Round 12
// baseline (155.171 us; speedup 1.0000x reference)
//
#include <hip/hip_runtime.h>
#include <hip/hip_bf16.h>

// AttentionHead: B=4, T=2048, C=1024, hs=64. All fp32 in/out.
#define D_MODEL 1024
#define HS 64
#define T_LEN 2048
#define JCH 256          // j-chunk width per attention block
#define NCH 8            // max chunks per row = T_LEN/JCH

typedef __attribute__((ext_vector_type(8))) short bf16x8;   // MFMA A/B frag
typedef __attribute__((ext_vector_type(4))) float f32x4;    // MFMA C/D frag

// split 8 floats into hi/lo bf16 (truncation split: residual exact)
__device__ inline void split8(const float* v, int4& hi, int4& lo) {
    union { unsigned short u[8]; int4 v4; } uh, ul;
    #pragma unroll
    for (int i = 0; i < 8; ++i) {
        const unsigned int b = __float_as_uint(v[i]);
        const unsigned short h = (unsigned short)(b >> 16);
        const float r = v[i] - __uint_as_float((unsigned int)h << 16);
        uh.u[i] = h;
        ul.u[i] = (unsigned short)(__float_as_uint(r) >> 16);
    }
    hi = uh.v4; lo = ul.v4;
}

// fp32 -> bf16 round-to-nearest-even (finite inputs only here)
__device__ inline unsigned short f2bf_rne(float f) {
    const unsigned int b = __float_as_uint(f);
    return (unsigned short)((b + 0x7FFFu + ((b >> 16) & 1u)) >> 16);
}
__device__ inline float bf2f(unsigned short h) {
    return __uint_as_float((unsigned int)h << 16);
}

// ---------------------------------------------------------------------------
// Kernel 0: W prep (coalesced) — UNCHANGED (passing).
// ---------------------------------------------------------------------------
__global__ __launch_bounds__(256) void wprep_kernel(
    const float* __restrict__ Wq, const float* __restrict__ Wk,
    const float* __restrict__ Wv, short* __restrict__ Wh, short* __restrict__ Wl)
{
    __shared__ float tile[64][69];
    const int tid = threadIdx.x;
    const int kb = blockIdx.x & 15;       // k-block 0..15
    const int m  = blockIdx.x >> 4;       // matrix 0..2
    const float* W = (m == 0) ? Wq : (m == 1) ? Wk : Wv;
    #pragma unroll
    for (int it = 0; it < 4; ++it) {
        const int idx = tid + 256 * it;
        const int kr = idx >> 4, c4 = idx & 15;
        *(float4*)&tile[kr][4 * c4] =
            *(const float4*)(W + (size_t)(kb * 64 + kr) * HS + 4 * c4);
    }
    __syncthreads();
    #pragma unroll
    for (int it = 0; it < 2; ++it) {
        const int s = tid + 256 * it;     // 0..511
        const int n = s >> 3, kc = s & 7;
        float v[8];
        #pragma unroll
        for (int i = 0; i < 8; ++i) v[i] = tile[kc * 8 + i][n];
        int4 hi, lo;
        split8(v, hi, lo);
        const size_t off = (size_t)(m * 64 + n) * D_MODEL + kb * 64 + kc * 8;
        *(int4*)(Wh + off) = hi;
        *(int4*)(Wl + off) = lo;
    }
}

// ---------------------------------------------------------------------------
// Kernel 1: QKV projection via split-bf16 MFMA.
// Grid (BT/32, 3) = 768 blocks x 256 threads -> 3 blocks/CU. Tile 32 M x
// 64 N; wave = 1 Mtile x 2 Ntiles. K-chunk 64 (2 sub-chunks of 32):
// 16 iterations -> half the barrier stalls of round 11, 12 MFMAs/iter/wave.
// All prefetch state in NAMED SCALAR registers (runtime-indexed register
// arrays go to scratch -> 77 MB HBM write amplification, round 10 lesson).
// ---------------------------------------------------------------------------
__global__ __launch_bounds__(256, 3) void qkv_kernel(
    const float* __restrict__ x,
    const short* __restrict__ Wh, const short* __restrict__ Wl,
    const float* __restrict__ bq, const float* __restrict__ bk,
    float* __restrict__ q, float* __restrict__ k, float* __restrict__ vt, int BT)
{
    __shared__ __align__(16) short Ah[4 * 520], Al[4 * 520];   // (mt*2+kc)
    __shared__ __align__(16) short Bh[8 * 520], Bl[8 * 520];   // (nt*2+kc)

    const int tid  = threadIdx.x;
    const int r0   = blockIdx.x * 32;
    const int nb   = blockIdx.y;          // col slice: global cols 64*nb ..
    const int wave = tid >> 6;
    const int lane = tid & 63;
    const int mt_w = wave >> 1;           // wave's Mtile (0..1)
    const int nt0  = (wave & 1) * 2;      // wave's first local ntile

    f32x4 acc0 = (f32x4)(0.f);
    f32x4 acc1 = (f32x4)(0.f);

    // A staging: one 32B x-read per thread (4 slots x 64 lanes = 256)
    const int amt = tid >> 7, akc = (tid >> 6) & 1, aln = tid & 63;
    const float* axsrc =
        x + (size_t)(r0 + amt * 16 + (aln & 15)) * D_MODEL + akc * 32 + (aln >> 4) * 8;

    // B staging: two slots per thread (8 slots x 64 lanes = 512)
    const int b0nt = tid >> 7, b0kc = (tid >> 6) & 1, b0ln = tid & 63;
    const size_t b0off =
        (size_t)(nb * 64 + b0nt * 16 + (b0ln & 15)) * D_MODEL + b0kc * 32 + (b0ln >> 4) * 8;
    const int b1nt = 2 + (tid >> 7);
    const size_t b1off =
        (size_t)(nb * 64 + b1nt * 16 + (b0ln & 15)) * D_MODEL + b0kc * 32 + (b0ln >> 4) * 8;

    // 1-deep prefetch in scalar registers
    float4 a0v = *(const float4*)(axsrc);
    float4 a1v = *(const float4*)(axsrc + 4);
    int4 pb0h = *(const int4*)(Wh + b0off);
    int4 pb0l = *(const int4*)(Wl + b0off);
    int4 pb1h = *(const int4*)(Wh + b1off);
    int4 pb1l = *(const int4*)(Wl + b1off);

    for (int k0 = 0; k0 < D_MODEL; k0 += 64) {
        __syncthreads();                  // prior iteration's LDS readers done
        // ---- write staged registers to LDS
        {
            float xv[8];
            *(float4*)&xv[0] = a0v;
            *(float4*)&xv[4] = a1v;
            int4 hi, lo;
            split8(xv, hi, lo);
            *(int4*)&Ah[(amt * 2 + akc) * 520 + aln * 8] = hi;
            *(int4*)&Al[(amt * 2 + akc) * 520 + aln * 8] = lo;
        }
        *(int4*)&Bh[(b0nt * 2 + b0kc) * 520 + b0ln * 8] = pb0h;
        *(int4*)&Bl[(b0nt * 2 + b0kc) * 520 + b0ln * 8] = pb0l;
        *(int4*)&Bh[(b1nt * 2 + b0kc) * 520 + b0ln * 8] = pb1h;
        *(int4*)&Bl[(b1nt * 2 + b0kc) * 520 + b0ln * 8] = pb1l;
        __syncthreads();                  // LDS ready
        // ---- preload next k-chunk (latency hides under MFMA below)
        const int kn = k0 + 64;
        if (kn < D_MODEL) {
            a0v = *(const float4*)(axsrc + kn);
            a1v = *(const float4*)(axsrc + kn + 4);
            pb0h = *(const int4*)(Wh + b0off + kn);
            pb0l = *(const int4*)(Wl + b0off + kn);
            pb1h = *(const int4*)(Wh + b1off + kn);
            pb1l = *(const int4*)(Wl + b1off + kn);
        }
        // ---- MFMA: 2 kc x (1 Mtile x 2 Ntiles x 3 split passes)
        #pragma unroll
        for (int kc = 0; kc < 2; ++kc) {
            const bf16x8 afh = *(const bf16x8*)&Ah[(mt_w * 2 + kc) * 520 + lane * 8];
            const bf16x8 afl = *(const bf16x8*)&Al[(mt_w * 2 + kc) * 520 + lane * 8];
            {
                const bf16x8 bfh = *(const bf16x8*)&Bh[(nt0 * 2 + kc) * 520 + lane * 8];
                const bf16x8 bfl = *(const bf16x8*)&Bl[(nt0 * 2 + kc) * 520 + lane * 8];
                acc0 = __builtin_amdgcn_mfma_f32_16x16x32_bf16(afh, bfh, acc0, 0, 0, 0);
                acc0 = __builtin_amdgcn_mfma_f32_16x16x32_bf16(afh, bfl, acc0, 0, 0, 0);
                acc0 = __builtin_amdgcn_mfma_f32_16x16x32_bf16(afl, bfh, acc0, 0, 0, 0);
            }
            {
                const bf16x8 bfh = *(const bf16x8*)&Bh[((nt0 + 1) * 2 + kc) * 520 + lane * 8];
                const bf16x8 bfl = *(const bf16x8*)&Bl[((nt0 + 1) * 2 + kc) * 520 + lane * 8];
                acc1 = __builtin_amdgcn_mfma_f32_16x16x32_bf16(afh, bfh, acc1, 0, 0, 0);
                acc1 = __builtin_amdgcn_mfma_f32_16x16x32_bf16(afh, bfl, acc1, 0, 0, 0);
                acc1 = __builtin_amdgcn_mfma_f32_16x16x32_bf16(afl, bfh, acc1, 0, 0, 0);
            }
        }
    }

    // ---- epilogue: C/D layout col=lane&15, row=(lane>>4)*4+reg
    const int rowb = r0 + mt_w * 16 + (lane >> 4) * 4;
    #pragma unroll
    for (int j = 0; j < 2; ++j) {
        const f32x4 a = (j == 0) ? acc0 : acc1;
        const int c = nb * 64 + (nt0 + j) * 16 + (lane & 15);
        if (c < 64) {
            const float bias = bq[c];
            #pragma unroll
            for (int r = 0; r < 4; ++r)
                q[(size_t)(rowb + r) * HS + c] = a[r] + bias;
        } else if (c < 128) {
            const float bias = bk[c - 64];
            #pragma unroll
            for (int r = 0; r < 4; ++r)
                k[(size_t)(rowb + r) * HS + (c - 64)] = a[r] + bias;
        } else {
            float4 o;
            o.x = a[0]; o.y = a[1]; o.z = a[2]; o.w = a[3];
            *(float4*)(vt + (size_t)(c - 128) * BT + rowb) = o;
        }
    }
}

// ---------------------------------------------------------------------------
// Kernel 2: flash-style attention via MFMA — round-8 structure; JCH now 256
// (NCH 8): live causal blocks ~330 -> ~576 (2.25/CU) for latency hiding.
// ---------------------------------------------------------------------------
__global__ __launch_bounds__(256) void attn_kernel(
    const float* __restrict__ q_ws, const float* __restrict__ k_ws,
    const float* __restrict__ vt_ws, const int* __restrict__ maskp,
    float* __restrict__ part_O, float* __restrict__ part_ml, int BT)
{
    __shared__ __align__(16) short Kh[4096], Kl[4096];
    __shared__ __align__(16) short Vt[4096];
    __shared__ __align__(16) short Pl[4][16 * 72];

    const int tile  = blockIdx.x;
    const int chunk = blockIdx.y;
    const int r0 = tile * 64;
    const int tb = r0 / T_LEN;
    const int t0 = r0 - tb * T_LEN;
    const int mask = (*maskp != 0);
    const int n_max = mask ? (t0 + 64) : T_LEN;
    const int j0 = chunk * JCH;
    if (j0 >= n_max) return;
    const int hi_j = min(j0 + JCH, n_max);
    const int njt = (hi_j - j0 + 63) >> 6;

    const int tid  = threadIdx.x;
    const int w    = tid >> 6;
    const int lane = tid & 63;
    const int quad = lane >> 4;
    const int l15  = lane & 15;
    const int rw0  = t0 + 16 * w;
    const int rowa = r0 + 16 * w + quad * 4;

    bf16x8 qfh[2], qfl[2];
    {
        const float* qrow = q_ws + (size_t)(r0 + 16 * w + l15) * HS + quad * 8;
        #pragma unroll
        for (int kc = 0; kc < 2; ++kc) {
            float v[8];
            *(float4*)&v[0] = *(const float4*)(qrow + kc * 32);
            *(float4*)&v[4] = *(const float4*)(qrow + kc * 32 + 4);
            union { int4 i; bf16x8 b; } ch, cl;
            split8(v, ch.i, cl.i);
            qfh[kc] = ch.b;
            qfl[kc] = cl.b;
        }
    }

    f32x4 oacc[4];
    #pragma unroll
    for (int nt = 0; nt < 4; ++nt) oacc[nt] = (f32x4)(0.f);
    float m_r[4] = {-INFINITY, -INFINITY, -INFINITY, -INFINITY};
    float l_r[4] = {0.f, 0.f, 0.f, 0.f};

    const float* kbase = k_ws + (size_t)tb * T_LEN * HS;

    for (int jt = 0; jt < njt; ++jt) {
        const int jbase = j0 + jt * 64;
        __syncthreads();
        #pragma unroll
        for (int it = 0; it < 2; ++it) {
            const int s  = tid + 256 * it;
            const int ls = s & 63;
            const int sc = s >> 6;
            const int jsub = sc >> 1, kc = sc & 1;
            const int jrow = jbase + jsub * 16 + (ls & 15);
            const int koff = kc * 32 + (ls >> 4) * 8;
            const float* src = kbase + (size_t)jrow * HS + koff;
            float v[8];
            *(float4*)&v[0] = *(const float4*)src;
            *(float4*)&v[4] = *(const float4*)(src + 4);
            int4 hi, lo;
            split8(v, hi, lo);
            *(int4*)&Kh[s * 8] = hi;
            *(int4*)&Kl[s * 8] = lo;
        }
        #pragma unroll
        for (int it = 0; it < 2; ++it) {
            const int s  = tid + 256 * it;
            const int ls = s & 63;
            const int sc = s >> 6;
            const int jc = sc >> 2, nt = sc & 3;
            const int n  = nt * 16 + (ls & 15);
            const int jcol = jbase + jc * 32 + (ls >> 4) * 8;
            const float* src = vt_ws + (size_t)n * BT + tb * T_LEN + jcol;
            float v[8];
            *(float4*)&v[0] = *(const float4*)src;
            *(float4*)&v[4] = *(const float4*)(src + 4);
            union { unsigned short u[8]; int4 i; } pk;
            #pragma unroll
            for (int i = 0; i < 8; ++i) pk.u[i] = f2bf_rne(v[i]);
            *(int4*)&Vt[s * 8] = pk.i;
        }
        __syncthreads();

        const bool active = (!mask) || (jbase <= rw0 + 15);
        if (active) {
            f32x4 sacc[4];
            #pragma unroll
            for (int jsub = 0; jsub < 4; ++jsub) {
                f32x4 s = (f32x4)(0.f);
                #pragma unroll
                for (int kc = 0; kc < 2; ++kc) {
                    const bf16x8 kh = *(const bf16x8*)&Kh[((jsub * 2 + kc) * 64 + lane) * 8];
                    const bf16x8 kl = *(const bf16x8*)&Kl[((jsub * 2 + kc) * 64 + lane) * 8];
                    s = __builtin_amdgcn_mfma_f32_16x16x32_bf16(qfh[kc], kh, s, 0, 0, 0);
                    s = __builtin_amdgcn_mfma_f32_16x16x32_bf16(qfh[kc], kl, s, 0, 0, 0);
                    s = __builtin_amdgcn_mfma_f32_16x16x32_bf16(qfl[kc], kh, s, 0, 0, 0);
                }
                sacc[jsub] = s;
            }
            float sval[4][4], rmax[4];
            #pragma unroll
            for (int r = 0; r < 4; ++r) rmax[r] = -INFINITY;
            #pragma unroll
            for (int jsub = 0; jsub < 4; ++jsub) {
                const int jg = jbase + jsub * 16 + l15;
                #pragma unroll
                for (int r = 0; r < 4; ++r) {
                    const int tg = rw0 + quad * 4 + r;
                    const float vv = (mask && (jg > tg)) ? -INFINITY : 8.0f * sacc[jsub][r];
                    sval[jsub][r] = vv;
                    rmax[r] = fmaxf(rmax[r], vv);
                }
            }
            #pragma unroll
            for (int d = 1; d < 16; d <<= 1)
                #pragma unroll
                for (int r = 0; r < 4; ++r)
                    rmax[r] = fmaxf(rmax[r], __shfl_xor(rmax[r], d));
            float alpha[4], msafe[4];
            #pragma unroll
            for (int r = 0; r < 4; ++r) {
                const float mn = fmaxf(m_r[r], rmax[r]);
                msafe[r] = (mn == -INFINITY) ? 0.f : mn;
                alpha[r] = __expf(m_r[r] - msafe[r]);
                m_r[r] = mn;
            }
            short* Pw = &Pl[w][0];
            float rsum[4] = {0.f, 0.f, 0.f, 0.f};
            #pragma unroll
            for (int jsub = 0; jsub < 4; ++jsub) {
                #pragma unroll
                for (int r = 0; r < 4; ++r) {
                    const float e = __expf(sval[jsub][r] - msafe[r]);
                    const unsigned short eb = f2bf_rne(e);
                    Pw[(quad * 4 + r) * 72 + jsub * 16 + l15] = (short)eb;
                    rsum[r] += bf2f(eb);
                }
            }
            #pragma unroll
            for (int d = 1; d < 16; d <<= 1)
                #pragma unroll
                for (int r = 0; r < 4; ++r)
                    rsum[r] += __shfl_xor(rsum[r], d);
            #pragma unroll
            for (int r = 0; r < 4; ++r)
                l_r[r] = l_r[r] * alpha[r] + rsum[r];
            #pragma unroll
            for (int nt = 0; nt < 4; ++nt)
                #pragma unroll
                for (int r = 0; r < 4; ++r)
                    oacc[nt][r] *= alpha[r];
            bf16x8 pf[2];
            #pragma unroll
            for (int jc = 0; jc < 2; ++jc)
                pf[jc] = *(const bf16x8*)&Pw[l15 * 72 + jc * 32 + quad * 8];
            #pragma unroll
            for (int nt = 0; nt < 4; ++nt) {
                #pragma unroll
                for (int jc = 0; jc < 2; ++jc) {
                    const bf16x8 vf = *(const bf16x8*)&Vt[((jc * 4 + nt) * 64 + lane) * 8];
                    oacc[nt] = __builtin_amdgcn_mfma_f32_16x16x32_bf16(pf[jc], vf, oacc[nt], 0, 0, 0);
                }
            }
        }
    }

    #pragma unroll
    for (int nt = 0; nt < 4; ++nt)
        #pragma unroll
        for (int r = 0; r < 4; ++r)
            part_O[((size_t)(rowa + r) * NCH + chunk) * HS + nt * 16 + l15] = oacc[nt][r];
    if (l15 == 0) {
        #pragma unroll
        for (int r = 0; r < 4; ++r) {
            float2 ml;
            ml.x = m_r[r];
            ml.y = l_r[r];
            *(float2*)(part_ml + ((size_t)(rowa + r) * NCH + chunk) * 2) = ml;
        }
    }
}

// ---------------------------------------------------------------------------
// Kernel 3: combine chunk partials. Two-pass over part_ml — NO runtime-
// indexed register arrays (scratch hazard, round 10 lesson).
// ---------------------------------------------------------------------------
__global__ __launch_bounds__(256) void combine_kernel(
    const float* __restrict__ part_O, const float* __restrict__ part_ml,
    const int* __restrict__ maskp, float* __restrict__ out)
{
    const int f = blockIdx.x * 256 + threadIdx.x;
    const int row = f >> 6;
    const int d = f & 63;
    const int t = row & (T_LEN - 1);
    const int mask = (*maskp != 0);
    const int n = mask ? (t + 1) : T_LEN;
    const int nc = (n + JCH - 1) / JCH;

    const float2* mlp = (const float2*)(part_ml + (size_t)row * NCH * 2);
    float M = -INFINITY;
    for (int c = 0; c < nc; ++c) M = fmaxf(M, mlp[c].x);
    float L = 0.f, O = 0.f;
    for (int c = 0; c < nc; ++c) {
        const float2 ml = mlp[c];
        const float w = __expf(ml.x - M);
        L += ml.y * w;
        O = fmaf(part_O[((size_t)row * NCH + c) * HS + d], w, O);
    }
    out[(size_t)row * HS + d] = O / L;
}

// ---------------------------------------------------------------------------
extern "C" void kernel_launch(void* const* d_in, const int* in_sizes, int n_in,
                              void* d_out, int out_size, void* d_ws, size_t ws_size,
                              hipStream_t stream) {
    const float* x  = (const float*)d_in[0];
    const float* Wq = (const float*)d_in[1];
    const float* bq = (const float*)d_in[2];
    const float* Wk = (const float*)d_in[3];
    const float* bk = (const float*)d_in[4];
    const float* Wv = (const float*)d_in[5];
    const int* maskp = (const int*)d_in[6];

    const int BT = in_sizes[0] / D_MODEL;   // 8192

    // ws layout (floats): q,k [BT*64], vt [64*BT], part_O [BT*NCH*64],
    // part_ml [BT*NCH*2]  (~24 MB total)
    float* q   = (float*)d_ws;
    float* k   = q + (size_t)BT * HS;
    float* vt  = k + (size_t)BT * HS;
    float* pO  = vt + (size_t)BT * HS;
    float* pml = pO + (size_t)BT * NCH * HS;

    // W split buffers ALIAS part_O (dead until attn_kernel runs, stream-ordered)
    short* Wh = (short*)pO;
    short* Wl = Wh + (size_t)192 * D_MODEL;

    wprep_kernel<<<48, 256, 0, stream>>>(Wq, Wk, Wv, Wh, Wl);
    dim3 qgrid(BT / 32, 3);
    qkv_kernel<<<qgrid, 256, 0, stream>>>(x, Wh, Wl, bq, bk, q, k, vt, BT);
    dim3 agrid(BT / 64, NCH);
    attn_kernel<<<agrid, 256, 0, stream>>>(q, k, vt, maskp, pO, pml, BT);
    combine_kernel<<<(BT * HS) / 256, 256, 0, stream>>>(pO, pml, maskp, (float*)d_out);
}

// Round 13
// 143.846 us; speedup vs baseline: 1.0787x; 1.0787x over previous
//
#include <hip/hip_runtime.h>
#include <hip/hip_bf16.h>

// AttentionHead: B=4, T=2048, C=1024, hs=64. All fp32 in/out.
#define D_MODEL 1024
#define HS 64
#define T_LEN 2048
#define JCH 512          // j-chunk width per attention block
#define NCH 4            // max chunks per row = T_LEN/JCH

typedef __attribute__((ext_vector_type(8))) short bf16x8;   // MFMA A/B frag
typedef __attribute__((ext_vector_type(4))) float f32x4;    // MFMA C/D frag

// split 8 floats into hi/lo bf16 (truncation split: residual exact)
__device__ inline void split8(const float* v, int4& hi, int4& lo) {
    union { unsigned short u[8]; int4 v4; } uh, ul;
    #pragma unroll
    for (int i = 0; i < 8; ++i) {
        const unsigned int b = __float_as_uint(v[i]);
        const unsigned short h = (unsigned short)(b >> 16);
        const float r = v[i] - __uint_as_float((unsigned int)h << 16);
        uh.u[i] = h;
        ul.u[i] = (unsigned short)(__float_as_uint(r) >> 16);
    }
    hi = uh.v4; lo = ul.v4;
}

// fp32 -> bf16 round-to-nearest-even (finite inputs only here)
__device__ inline unsigned short f2bf_rne(float f) {
    const unsigned int b = __float_as_uint(f);
    return (unsigned short)((b + 0x7FFFu + ((b >> 16) & 1u)) >> 16);
}
__device__ inline float bf2f(unsigned short h) {
    return __uint_as_float((unsigned int)h << 16);
}

// async 16B global -> LDS (direct-to-shared DMA). LDS dest is wave-uniform
// base; HW writes ldsbase + lane*16. gptr is per-lane.
__device__ inline void async_copy16(const short* g, short* l) {
    __builtin_amdgcn_global_load_lds(
        (const __attribute__((address_space(1))) void*)g,
        (__attribute__((address_space(3))) void*)l, 16, 0, 0);
}

// ---------------------------------------------------------------------------
// Kernel 0: prep — pre-split x and W into FRAGMENT-ORDERED bf16 hi/lo.
// Layouts (shorts): xf[mtg][kc][lane][8] at ((mtg*32+kc)*64+lane)*8 where
//   row = mtg*16 + (lane&15), col = kc*32 + (lane>>4)*8 + e.
// wf[ntg][kc][lane][8] same scheme, ntg = global 16-col tile (0..11).
// Blocks 0..BT/16-1: x tiles. Blocks BT/16..BT/16+47: W tiles (64k x 64n).
// ---------------------------------------------------------------------------
__global__ __launch_bounds__(256) void prep_kernel(
    const float* __restrict__ x,
    const float* __restrict__ Wq, const float* __restrict__ Wk,
    const float* __restrict__ Wv,
    short* __restrict__ xh, short* __restrict__ xl,
    short* __restrict__ wh, short* __restrict__ wl, int BT)
{
    __shared__ float tile[64][69];
    const int tid = threadIdx.x;
    const int bx  = blockIdx.x;
    const int nxb = BT >> 4;

    if (bx < nxb) {
        // ---- x conversion: 2048 slots (32 kc x 64 lanes), 8 per thread
        const int mtg = bx;
        #pragma unroll
        for (int i = 0; i < 8; ++i) {
            const int s    = tid + 256 * i;
            const int kc   = s >> 6;
            const int lane = s & 63;
            const float* src = x + (size_t)(mtg * 16 + (lane & 15)) * D_MODEL
                                 + kc * 32 + (lane >> 4) * 8;
            float v[8];
            *(float4*)&v[0] = *(const float4*)src;
            *(float4*)&v[4] = *(const float4*)(src + 4);
            int4 hi, lo;
            split8(v, hi, lo);
            const size_t off = ((size_t)(mtg * 32 + kc) * 64 + lane) * 8;
            *(int4*)(xh + off) = hi;
            *(int4*)(xl + off) = lo;
        }
    } else {
        // ---- W conversion: one 64k x 64n tile, via LDS transpose
        const int wb = bx - nxb;
        const int kb = wb & 15;           // k-block 0..15
        const int m  = wb >> 4;           // matrix 0..2
        const float* W = (m == 0) ? Wq : (m == 1) ? Wk : Wv;
        #pragma unroll
        for (int it = 0; it < 4; ++it) {
            const int idx = tid + 256 * it;
            const int kr = idx >> 4, c4 = idx & 15;
            *(float4*)&tile[kr][4 * c4] =
                *(const float4*)(W + (size_t)(kb * 64 + kr) * HS + 4 * c4);
        }
        __syncthreads();
        #pragma unroll
        for (int i = 0; i < 2; ++i) {
            const int s    = tid + 256 * i;    // 0..511
            const int ntl  = s >> 7;           // 0..3
            const int kcl  = (s >> 6) & 1;
            const int lane = s & 63;
            const int n    = ntl * 16 + (lane & 15);
            const int krel = kcl * 32 + (lane >> 4) * 8;
            float v[8];
            #pragma unroll
            for (int e = 0; e < 8; ++e) v[e] = tile[krel + e][n];
            int4 hi, lo;
            split8(v, hi, lo);
            const size_t off =
                ((size_t)((m * 4 + ntl) * 32 + kb * 2 + kcl) * 64 + lane) * 8;
            *(int4*)(wh + off) = hi;
            *(int4*)(wl + off) = lo;
        }
    }
}

// ---------------------------------------------------------------------------
// Kernel 1: QKV projection via split-bf16 MFMA, m97-style staging:
// operands pre-converted to fragment order, staged by global_load_lds
// (async direct-to-LDS, no VGPR round trip, no VALU converts in loop).
// Grid (BT/32, 3) = 768 blocks x 256 threads. Tile 32 M x 64 N; wave =
// 1 Mtile x 2 Ntiles; K=64 per iteration (16 iterations, 2 barriers each).
// 24 staging wave-ops/iter split 6 per wave. LDS 24 KB, no padding
// (lane-linear is required by global_load_lds and fine for ds_read_b128).
// ---------------------------------------------------------------------------
__global__ __launch_bounds__(256) void qkv_kernel(
    const short* __restrict__ xh, const short* __restrict__ xl,
    const short* __restrict__ wh, const short* __restrict__ wl,
    const float* __restrict__ bq, const float* __restrict__ bk,
    float* __restrict__ q, float* __restrict__ k, float* __restrict__ vt, int BT)
{
    // A groups: g = mt*4 + kcl*2 + p (8 x 512 shorts)
    // B groups: gb = nt*4 + kcl*2 + p (16 x 512 shorts)
    __shared__ __align__(16) short A_lds[8 * 512];
    __shared__ __align__(16) short B_lds[16 * 512];

    const int tid  = threadIdx.x;
    const int r0   = blockIdx.x * 32;
    const int nb   = blockIdx.y;          // col slice: global cols 64*nb ..
    const int wave = tid >> 6;
    const int lane = tid & 63;
    const int mt_w = wave >> 1;           // wave's Mtile (0..1)
    const int nt0  = (wave & 1) * 2;      // wave's first local ntile

    f32x4 acc0 = (f32x4)(0.f);
    f32x4 acc1 = (f32x4)(0.f);

    const size_t mtg0 = (size_t)(r0 >> 4);
    const size_t ntg0 = (size_t)(nb * 4);

    for (int k0 = 0; k0 < D_MODEL; k0 += 64) {
        const int kc0 = k0 >> 5;
        __syncthreads();                  // prior iteration's LDS readers done
        // ---- issue 6 async 1KB stages for this wave (wave-uniform LDS base)
        #pragma unroll
        for (int ii = 0; ii < 6; ++ii) {
            const int g = wave * 6 + ii;
            if (g < 8) {
                const int mt = g >> 2, kcl = (g >> 1) & 1, p = g & 1;
                const short* base = p ? xl : xh;
                const short* gsrc = base + ((mtg0 + mt) * 32 + kc0 + kcl) * 512;
                async_copy16(gsrc + lane * 8, &A_lds[g * 512]);
            } else {
                const int gb = g - 8;
                const int nt = gb >> 2, kcl = (gb >> 1) & 1, p = gb & 1;
                const short* base = p ? wl : wh;
                const short* gsrc = base + ((ntg0 + nt) * 32 + kc0 + kcl) * 512;
                async_copy16(gsrc + lane * 8, &B_lds[gb * 512]);
            }
        }
        __syncthreads();                  // drains vmcnt -> LDS ready
        // ---- MFMA: 2 kcl x (1 Mtile x 2 Ntiles x 3 split passes)
        #pragma unroll
        for (int kcl = 0; kcl < 2; ++kcl) {
            const bf16x8 afh = *(const bf16x8*)&A_lds[(mt_w * 4 + kcl * 2 + 0) * 512 + lane * 8];
            const bf16x8 afl = *(const bf16x8*)&A_lds[(mt_w * 4 + kcl * 2 + 1) * 512 + lane * 8];
            {
                const bf16x8 bfh = *(const bf16x8*)&B_lds[(nt0 * 4 + kcl * 2 + 0) * 512 + lane * 8];
                const bf16x8 bfl = *(const bf16x8*)&B_lds[(nt0 * 4 + kcl * 2 + 1) * 512 + lane * 8];
                acc0 = __builtin_amdgcn_mfma_f32_16x16x32_bf16(afh, bfh, acc0, 0, 0, 0);
                acc0 = __builtin_amdgcn_mfma_f32_16x16x32_bf16(afh, bfl, acc0, 0, 0, 0);
                acc0 = __builtin_amdgcn_mfma_f32_16x16x32_bf16(afl, bfh, acc0, 0, 0, 0);
            }
            {
                const bf16x8 bfh = *(const bf16x8*)&B_lds[((nt0 + 1) * 4 + kcl * 2 + 0) * 512 + lane * 8];
                const bf16x8 bfl = *(const bf16x8*)&B_lds[((nt0 + 1) * 4 + kcl * 2 + 1) * 512 + lane * 8];
                acc1 = __builtin_amdgcn_mfma_f32_16x16x32_bf16(afh, bfh, acc1, 0, 0, 0);
                acc1 = __builtin_amdgcn_mfma_f32_16x16x32_bf16(afh, bfl, acc1, 0, 0, 0);
                acc1 = __builtin_amdgcn_mfma_f32_16x16x32_bf16(afl, bfh, acc1, 0, 0, 0);
            }
        }
    }

    // ---- epilogue: C/D layout col=lane&15, row=(lane>>4)*4+reg
    const int rowb = r0 + mt_w * 16 + (lane >> 4) * 4;
    #pragma unroll
    for (int j = 0; j < 2; ++j) {
        const f32x4 a = (j == 0) ? acc0 : acc1;
        const int c = nb * 64 + (nt0 + j) * 16 + (lane & 15);
        if (c < 64) {
            const float bias = bq[c];
            #pragma unroll
            for (int r = 0; r < 4; ++r)
                q[(size_t)(rowb + r) * HS + c] = a[r] + bias;
        } else if (c < 128) {
            const float bias = bk[c - 64];
            #pragma unroll
            for (int r = 0; r < 4; ++r)
                k[(size_t)(rowb + r) * HS + (c - 64)] = a[r] + bias;
        } else {
            float4 o;
            o.x = a[0]; o.y = a[1]; o.z = a[2]; o.w = a[3];
            *(float4*)(vt + (size_t)(c - 128) * BT + rowb) = o;
        }
    }
}

// ---------------------------------------------------------------------------
// Kernel 2: flash-style attention via MFMA — round-8 version (JCH 512),
// UNCHANGED (part of the 151/156 µs passing runs).
// ---------------------------------------------------------------------------
__global__ __launch_bounds__(256) void attn_kernel(
    const float* __restrict__ q_ws, const float* __restrict__ k_ws,
    const float* __restrict__ vt_ws, const int* __restrict__ maskp,
    float* __restrict__ part_O, float* __restrict__ part_ml, int BT)
{
    __shared__ __align__(16) short Kh[4096], Kl[4096];
    __shared__ __align__(16) short Vt[4096];
    __shared__ __align__(16) short Pl[4][16 * 72];

    const int tile  = blockIdx.x;
    const int chunk = blockIdx.y;
    const int r0 = tile * 64;
    const int tb = r0 / T_LEN;
    const int t0 = r0 - tb * T_LEN;
    const int mask = (*maskp != 0);
    const int n_max = mask ? (t0 + 64) : T_LEN;
    const int j0 = chunk * JCH;
    if (j0 >= n_max) return;
    const int hi_j = min(j0 + JCH, n_max);
    const int njt = (hi_j - j0 + 63) >> 6;

    const int tid  = threadIdx.x;
    const int w    = tid >> 6;
    const int lane = tid & 63;
    const int quad = lane >> 4;
    const int l15  = lane & 15;
    const int rw0  = t0 + 16 * w;
    const int rowa = r0 + 16 * w + quad * 4;

    bf16x8 qfh[2], qfl[2];
    {
        const float* qrow = q_ws + (size_t)(r0 + 16 * w + l15) * HS + quad * 8;
        #pragma unroll
        for (int kc = 0; kc < 2; ++kc) {
            float v[8];
            *(float4*)&v[0] = *(const float4*)(qrow + kc * 32);
            *(float4*)&v[4] = *(const float4*)(qrow + kc * 32 + 4);
            union { int4 i; bf16x8 b; } ch, cl;
            split8(v, ch.i, cl.i);
            qfh[kc] = ch.b;
            qfl[kc] = cl.b;
        }
    }

    f32x4 oacc[4];
    #pragma unroll
    for (int nt = 0; nt < 4; ++nt) oacc[nt] = (f32x4)(0.f);
    float m_r[4] = {-INFINITY, -INFINITY, -INFINITY, -INFINITY};
    float l_r[4] = {0.f, 0.f, 0.f, 0.f};

    const float* kbase = k_ws + (size_t)tb * T_LEN * HS;

    for (int jt = 0; jt < njt; ++jt) {
        const int jbase = j0 + jt * 64;
        __syncthreads();
        #pragma unroll
        for (int it = 0; it < 2; ++it) {
            const int s  = tid + 256 * it;
            const int ls = s & 63;
            const int sc = s >> 6;
            const int jsub = sc >> 1, kc = sc & 1;
            const int jrow = jbase + jsub * 16 + (ls & 15);
            const int koff = kc * 32 + (ls >> 4) * 8;
            const float* src = kbase + (size_t)jrow * HS + koff;
            float v[8];
            *(float4*)&v[0] = *(const float4*)src;
            *(float4*)&v[4] = *(const float4*)(src + 4);
            int4 hi, lo;
            split8(v, hi, lo);
            *(int4*)&Kh[s * 8] = hi;
            *(int4*)&Kl[s * 8] = lo;
        }
        #pragma unroll
        for (int it = 0; it < 2; ++it) {
            const int s  = tid + 256 * it;
            const int ls = s & 63;
            const int sc = s >> 6;
            const int jc = sc >> 2, nt = sc & 3;
            const int n  = nt * 16 + (ls & 15);
            const int jcol = jbase + jc * 32 + (ls >> 4) * 8;
            const float* src = vt_ws + (size_t)n * BT + tb * T_LEN + jcol;
            float v[8];
            *(float4*)&v[0] = *(const float4*)src;
            *(float4*)&v[4] = *(const float4*)(src + 4);
            union { unsigned short u[8]; int4 i; } pk;
            #pragma unroll
            for (int i = 0; i < 8; ++i) pk.u[i] = f2bf_rne(v[i]);
            *(int4*)&Vt[s * 8] = pk.i;
        }
        __syncthreads();

        const bool active = (!mask) || (jbase <= rw0 + 15);
        if (active) {
            f32x4 sacc[4];
            #pragma unroll
            for (int jsub = 0; jsub < 4; ++jsub) {
                f32x4 s = (f32x4)(0.f);
                #pragma unroll
                for (int kc = 0; kc < 2; ++kc) {
                    const bf16x8 kh = *(const bf16x8*)&Kh[((jsub * 2 + kc) * 64 + lane) * 8];
                    const bf16x8 kl = *(const bf16x8*)&Kl[((jsub * 2 + kc) * 64 + lane) * 8];
                    s = __builtin_amdgcn_mfma_f32_16x16x32_bf16(qfh[kc], kh, s, 0, 0, 0);
                    s = __builtin_amdgcn_mfma_f32_16x16x32_bf16(qfh[kc], kl, s, 0, 0, 0);
                    s = __builtin_amdgcn_mfma_f32_16x16x32_bf16(qfl[kc], kh, s, 0, 0, 0);
                }
                sacc[jsub] = s;
            }
            float sval[4][4], rmax[4];
            #pragma unroll
            for (int r = 0; r < 4; ++r) rmax[r] = -INFINITY;
            #pragma unroll
            for (int jsub = 0; jsub < 4; ++jsub) {
                const int jg = jbase + jsub * 16 + l15;
                #pragma unroll
                for (int r = 0; r < 4; ++r) {
                    const int tg = rw0 + quad * 4 + r;
                    const float vv = (mask && (jg > tg)) ? -INFINITY : 8.0f * sacc[jsub][r];
                    sval[jsub][r] = vv;
                    rmax[r] = fmaxf(rmax[r], vv);
                }
            }
            #pragma unroll
            for (int d = 1; d < 16; d <<= 1)
                #pragma unroll
                for (int r = 0; r < 4; ++r)
                    rmax[r] = fmaxf(rmax[r], __shfl_xor(rmax[r], d));
            float alpha[4], msafe[4];
            #pragma unroll
            for (int r = 0; r < 4; ++r) {
                const float mn = fmaxf(m_r[r], rmax[r]);
                msafe[r] = (mn == -INFINITY) ? 0.f : mn;
                alpha[r] = __expf(m_r[r] - msafe[r]);
                m_r[r] = mn;
            }
            short* Pw = &Pl[w][0];
            float rsum[4] = {0.f, 0.f, 0.f, 0.f};
            #pragma unroll
            for (int jsub = 0; jsub < 4; ++jsub) {
                #pragma unroll
                for (int r = 0; r < 4; ++r) {
                    const float e = __expf(sval[jsub][r] - msafe[r]);
                    const unsigned short eb = f2bf_rne(e);
                    Pw[(quad * 4 + r) * 72 + jsub * 16 + l15] = (short)eb;
                    rsum[r] += bf2f(eb);
                }
            }
            #pragma unroll
            for (int d = 1; d < 16; d <<= 1)
                #pragma unroll
                for (int r = 0; r < 4; ++r)
                    rsum[r] += __shfl_xor(rsum[r], d);
            #pragma unroll
            for (int r = 0; r < 4; ++r)
                l_r[r] = l_r[r] * alpha[r] + rsum[r];
            #pragma unroll
            for (int nt = 0; nt < 4; ++nt)
                #pragma unroll
                for (int r = 0; r < 4; ++r)
                    oacc[nt][r] *= alpha[r];
            bf16x8 pf[2];
            #pragma unroll
            for (int jc = 0; jc < 2; ++jc)
                pf[jc] = *(const bf16x8*)&Pw[l15 * 72 + jc * 32 + quad * 8];
            #pragma unroll
            for (int nt = 0; nt < 4; ++nt) {
                #pragma unroll
                for (int jc = 0; jc < 2; ++jc) {
                    const bf16x8 vf = *(const bf16x8*)&Vt[((jc * 4 + nt) * 64 + lane) * 8];
                    oacc[nt] = __builtin_amdgcn_mfma_f32_16x16x32_bf16(pf[jc], vf, oacc[nt], 0, 0, 0);
                }
            }
        }
    }

    #pragma unroll
    for (int nt = 0; nt < 4; ++nt)
        #pragma unroll
        for (int r = 0; r < 4; ++r)
            part_O[((size_t)(rowa + r) * NCH + chunk) * HS + nt * 16 + l15] = oacc[nt][r];
    if (l15 == 0) {
        #pragma unroll
        for (int r = 0; r < 4; ++r) {
            float2 ml;
            ml.x = m_r[r];
            ml.y = l_r[r];
            *(float2*)(part_ml + ((size_t)(rowa + r) * NCH + chunk) * 2) = ml;
        }
    }
}

// ---------------------------------------------------------------------------
// Kernel 3: combine chunk partials. Two-pass over part_ml — NO runtime-
// indexed register arrays (scratch hazard, round 10 lesson).
// ---------------------------------------------------------------------------
__global__ __launch_bounds__(256) void combine_kernel(
    const float* __restrict__ part_O, const float* __restrict__ part_ml,
    const int* __restrict__ maskp, float* __restrict__ out)
{
    const int f = blockIdx.x * 256 + threadIdx.x;
    const int row = f >> 6;
    const int d = f & 63;
    const int t = row & (T_LEN - 1);
    const int mask = (*maskp != 0);
    const int n = mask ? (t + 1) : T_LEN;
    const int nc = (n + JCH - 1) / JCH;

    const float2* mlp = (const float2*)(part_ml + (size_t)row * NCH * 2);
    float M = -INFINITY;
    for (int c = 0; c < nc; ++c) M = fmaxf(M, mlp[c].x);
    float L = 0.f, O = 0.f;
    for (int c = 0; c < nc; ++c) {
        const float2 ml = mlp[c];
        const float w = __expf(ml.x - M);
        L += ml.y * w;
        O = fmaf(part_O[((size_t)row * NCH + c) * HS + d], w, O);
    }
    out[(size_t)row * HS + d] = O / L;
}

// ---------------------------------------------------------------------------
extern "C" void kernel_launch(void* const* d_in, const int* in_sizes, int n_in,
                              void* d_out, int out_size, void* d_ws, size_t ws_size,
                              hipStream_t stream) {
    const float* x  = (const float*)d_in[0];
    const float* Wq = (const float*)d_in[1];
    const float* bq = (const float*)d_in[2];
    const float* Wk = (const float*)d_in[3];
    const float* bk = (const float*)d_in[4];
    const float* Wv = (const float*)d_in[5];
    const int* maskp = (const int*)d_in[6];

    const int BT = in_sizes[0] / D_MODEL;   // 8192

    // ws layout: floats q,k [BT*64], vt [64*BT], pO [BT*NCH*64], pml [BT*NCH*2];
    // then shorts xh,xl [BT*1024 each], wh,wl [192*1024 each]. ~48 MB total.
    float* q   = (float*)d_ws;
    float* k   = q + (size_t)BT * HS;
    float* vt  = k + (size_t)BT * HS;
    float* pO  = vt + (size_t)BT * HS;
    float* pml = pO + (size_t)BT * NCH * HS;
    short* xh  = (short*)(pml + (size_t)BT * NCH * 2);
    short* xl  = xh + (size_t)BT * D_MODEL;
    short* wh  = xl + (size_t)BT * D_MODEL;
    short* wl  = wh + (size_t)192 * D_MODEL;

    prep_kernel<<<BT / 16 + 48, 256, 0, stream>>>(x, Wq, Wk, Wv, xh, xl, wh, wl, BT);
    dim3 qgrid(BT / 32, 3);
    qkv_kernel<<<qgrid, 256, 0, stream>>>(xh, xl, wh, wl, bq, bk, q, k, vt, BT);
    dim3 agrid(BT / 64, NCH);
    attn_kernel<<<agrid, 256, 0, stream>>>(q, k, vt, maskp, pO, pml, BT);
    combine_kernel<<<(BT * HS) / 256, 256, 0, stream>>>(pO, pml, maskp, (float*)d_out);
}

// Round 14
// 140.350 us; speedup vs baseline: 1.1056x; 1.0249x over previous
//
#include <hip/hip_runtime.h>
#include <hip/hip_bf16.h>

// AttentionHead: B=4, T=2048, C=1024, hs=64. All fp32 in/out.
#define D_MODEL 1024
#define HS 64
#define T_LEN 2048
#define JCH 512          // j-chunk width per attention block
#define NCH 4            // max chunks per row = T_LEN/JCH

typedef __attribute__((ext_vector_type(8))) short bf16x8;   // MFMA A/B frag
typedef __attribute__((ext_vector_type(4))) float f32x4;    // MFMA C/D frag

// split 8 floats into hi/lo bf16 (truncation split: residual exact)
__device__ inline void split8(const float* v, int4& hi, int4& lo) {
    union { unsigned short u[8]; int4 v4; } uh, ul;
    #pragma unroll
    for (int i = 0; i < 8; ++i) {
        const unsigned int b = __float_as_uint(v[i]);
        const unsigned short h = (unsigned short)(b >> 16);
        const float r = v[i] - __uint_as_float((unsigned int)h << 16);
        uh.u[i] = h;
        ul.u[i] = (unsigned short)(__float_as_uint(r) >> 16);
    }
    hi = uh.v4; lo = ul.v4;
}

// fp32 -> bf16 round-to-nearest-even (finite inputs only here)
__device__ inline unsigned short f2bf_rne(float f) {
    const unsigned int b = __float_as_uint(f);
    return (unsigned short)((b + 0x7FFFu + ((b >> 16) & 1u)) >> 16);
}
__device__ inline float bf2f(unsigned short h) {
    return __uint_as_float((unsigned int)h << 16);
}

// async 16B global -> LDS (direct-to-shared DMA). LDS dest is wave-uniform
// base; HW writes ldsbase + lane*16. gptr is per-lane.
__device__ inline void async_copy16(const short* g, short* l) {
    __builtin_amdgcn_global_load_lds(
        (const __attribute__((address_space(1))) void*)g,
        (__attribute__((address_space(3))) void*)l, 16, 0, 0);
}

// ---------------------------------------------------------------------------
// Kernel 0: prep — pre-split x and W into FRAGMENT-ORDERED bf16 hi/lo.
// (UNCHANGED from round 13 — passing.)
// ---------------------------------------------------------------------------
__global__ __launch_bounds__(256) void prep_kernel(
    const float* __restrict__ x,
    const float* __restrict__ Wq, const float* __restrict__ Wk,
    const float* __restrict__ Wv,
    short* __restrict__ xh, short* __restrict__ xl,
    short* __restrict__ wh, short* __restrict__ wl, int BT)
{
    __shared__ float tile[64][69];
    const int tid = threadIdx.x;
    const int bx  = blockIdx.x;
    const int nxb = BT >> 4;

    if (bx < nxb) {
        const int mtg = bx;
        #pragma unroll
        for (int i = 0; i < 8; ++i) {
            const int s    = tid + 256 * i;
            const int kc   = s >> 6;
            const int lane = s & 63;
            const float* src = x + (size_t)(mtg * 16 + (lane & 15)) * D_MODEL
                                 + kc * 32 + (lane >> 4) * 8;
            float v[8];
            *(float4*)&v[0] = *(const float4*)src;
            *(float4*)&v[4] = *(const float4*)(src + 4);
            int4 hi, lo;
            split8(v, hi, lo);
            const size_t off = ((size_t)(mtg * 32 + kc) * 64 + lane) * 8;
            *(int4*)(xh + off) = hi;
            *(int4*)(xl + off) = lo;
        }
    } else {
        const int wb = bx - nxb;
        const int kb = wb & 15;           // k-block 0..15
        const int m  = wb >> 4;           // matrix 0..2
        const float* W = (m == 0) ? Wq : (m == 1) ? Wk : Wv;
        #pragma unroll
        for (int it = 0; it < 4; ++it) {
            const int idx = tid + 256 * it;
            const int kr = idx >> 4, c4 = idx & 15;
            *(float4*)&tile[kr][4 * c4] =
                *(const float4*)(W + (size_t)(kb * 64 + kr) * HS + 4 * c4);
        }
        __syncthreads();
        #pragma unroll
        for (int i = 0; i < 2; ++i) {
            const int s    = tid + 256 * i;    // 0..511
            const int ntl  = s >> 7;           // 0..3
            const int kcl  = (s >> 6) & 1;
            const int lane = s & 63;
            const int n    = ntl * 16 + (lane & 15);
            const int krel = kcl * 32 + (lane >> 4) * 8;
            float v[8];
            #pragma unroll
            for (int e = 0; e < 8; ++e) v[e] = tile[krel + e][n];
            int4 hi, lo;
            split8(v, hi, lo);
            const size_t off =
                ((size_t)((m * 4 + ntl) * 32 + kb * 2 + kcl) * 64 + lane) * 8;
            *(int4*)(wh + off) = hi;
            *(int4*)(wl + off) = lo;
        }
    }
}

// ---------------------------------------------------------------------------
// Kernel 1: QKV projection — UNCHANGED from round 13 (passing, async staging).
// ---------------------------------------------------------------------------
__global__ __launch_bounds__(256) void qkv_kernel(
    const short* __restrict__ xh, const short* __restrict__ xl,
    const short* __restrict__ wh, const short* __restrict__ wl,
    const float* __restrict__ bq, const float* __restrict__ bk,
    float* __restrict__ q, float* __restrict__ k, float* __restrict__ vt, int BT)
{
    __shared__ __align__(16) short A_lds[8 * 512];
    __shared__ __align__(16) short B_lds[16 * 512];

    const int tid  = threadIdx.x;
    const int r0   = blockIdx.x * 32;
    const int nb   = blockIdx.y;
    const int wave = tid >> 6;
    const int lane = tid & 63;
    const int mt_w = wave >> 1;
    const int nt0  = (wave & 1) * 2;

    f32x4 acc0 = (f32x4)(0.f);
    f32x4 acc1 = (f32x4)(0.f);

    const size_t mtg0 = (size_t)(r0 >> 4);
    const size_t ntg0 = (size_t)(nb * 4);

    for (int k0 = 0; k0 < D_MODEL; k0 += 64) {
        const int kc0 = k0 >> 5;
        __syncthreads();
        #pragma unroll
        for (int ii = 0; ii < 6; ++ii) {
            const int g = wave * 6 + ii;
            if (g < 8) {
                const int mt = g >> 2, kcl = (g >> 1) & 1, p = g & 1;
                const short* base = p ? xl : xh;
                const short* gsrc = base + ((mtg0 + mt) * 32 + kc0 + kcl) * 512;
                async_copy16(gsrc + lane * 8, &A_lds[g * 512]);
            } else {
                const int gb = g - 8;
                const int nt = gb >> 2, kcl = (gb >> 1) & 1, p = gb & 1;
                const short* base = p ? wl : wh;
                const short* gsrc = base + ((ntg0 + nt) * 32 + kc0 + kcl) * 512;
                async_copy16(gsrc + lane * 8, &B_lds[gb * 512]);
            }
        }
        __syncthreads();
        #pragma unroll
        for (int kcl = 0; kcl < 2; ++kcl) {
            const bf16x8 afh = *(const bf16x8*)&A_lds[(mt_w * 4 + kcl * 2 + 0) * 512 + lane * 8];
            const bf16x8 afl = *(const bf16x8*)&A_lds[(mt_w * 4 + kcl * 2 + 1) * 512 + lane * 8];
            {
                const bf16x8 bfh = *(const bf16x8*)&B_lds[(nt0 * 4 + kcl * 2 + 0) * 512 + lane * 8];
                const bf16x8 bfl = *(const bf16x8*)&B_lds[(nt0 * 4 + kcl * 2 + 1) * 512 + lane * 8];
                acc0 = __builtin_amdgcn_mfma_f32_16x16x32_bf16(afh, bfh, acc0, 0, 0, 0);
                acc0 = __builtin_amdgcn_mfma_f32_16x16x32_bf16(afh, bfl, acc0, 0, 0, 0);
                acc0 = __builtin_amdgcn_mfma_f32_16x16x32_bf16(afl, bfh, acc0, 0, 0, 0);
            }
            {
                const bf16x8 bfh = *(const bf16x8*)&B_lds[((nt0 + 1) * 4 + kcl * 2 + 0) * 512 + lane * 8];
                const bf16x8 bfl = *(const bf16x8*)&B_lds[((nt0 + 1) * 4 + kcl * 2 + 1) * 512 + lane * 8];
                acc1 = __builtin_amdgcn_mfma_f32_16x16x32_bf16(afh, bfh, acc1, 0, 0, 0);
                acc1 = __builtin_amdgcn_mfma_f32_16x16x32_bf16(afh, bfl, acc1, 0, 0, 0);
                acc1 = __builtin_amdgcn_mfma_f32_16x16x32_bf16(afl, bfh, acc1, 0, 0, 0);
            }
        }
    }

    const int rowb = r0 + mt_w * 16 + (lane >> 4) * 4;
    #pragma unroll
    for (int j = 0; j < 2; ++j) {
        const f32x4 a = (j == 0) ? acc0 : acc1;
        const int c = nb * 64 + (nt0 + j) * 16 + (lane & 15);
        if (c < 64) {
            const float bias = bq[c];
            #pragma unroll
            for (int r = 0; r < 4; ++r)
                q[(size_t)(rowb + r) * HS + c] = a[r] + bias;
        } else if (c < 128) {
            const float bias = bk[c - 64];
            #pragma unroll
            for (int r = 0; r < 4; ++r)
                k[(size_t)(rowb + r) * HS + (c - 64)] = a[r] + bias;
        } else {
            float4 o;
            o.x = a[0]; o.y = a[1]; o.z = a[2]; o.w = a[3];
            *(float4*)(vt + (size_t)(c - 128) * BT + rowb) = o;
        }
    }
}

// ---------------------------------------------------------------------------
// Kernel 1b: kvprep — convert k (fp32 row-major) to fragment-ordered split
// bf16 kfh/kfl ([ktile][kc][lane][8]; ktile = global row/16), and vt (fp32
// [64][BT]) to fragment-ordered RNE bf16 vf ([vtile64][jc*4+nt][lane][8]).
// Values bit-identical to attn's former in-loop conversions.
// ---------------------------------------------------------------------------
__global__ __launch_bounds__(256) void kvprep_kernel(
    const float* __restrict__ k, const float* __restrict__ vt,
    short* __restrict__ kfh, short* __restrict__ kfl, short* __restrict__ vf,
    int BT)
{
    const int tid = threadIdx.x;
    const int bx  = blockIdx.x;
    const int nkb = BT >> 6;            // K blocks: 64 rows each

    if (bx < nkb) {
        #pragma unroll
        for (int i = 0; i < 2; ++i) {
            const int s    = tid + 256 * i;     // 0..511
            const int tl   = s >> 7;            // 0..3 (16-row subtile)
            const int kc   = (s >> 6) & 1;
            const int lane = s & 63;
            const int row  = bx * 64 + tl * 16 + (lane & 15);
            const int col  = kc * 32 + (lane >> 4) * 8;
            const float* src = k + (size_t)row * HS + col;
            float v[8];
            *(float4*)&v[0] = *(const float4*)src;
            *(float4*)&v[4] = *(const float4*)(src + 4);
            int4 hi, lo;
            split8(v, hi, lo);
            const size_t off = (((size_t)(bx * 4 + tl) * 2 + kc) * 64 + lane) * 8;
            *(int4*)(kfh + off) = hi;
            *(int4*)(kfl + off) = lo;
        }
    } else {
        const int vb = bx - nkb;            // 64-j tile: global j base vb*64
        #pragma unroll
        for (int i = 0; i < 2; ++i) {
            const int s    = tid + 256 * i;     // 0..511
            const int gg   = s >> 6;            // jc*4+nt
            const int lane = s & 63;
            const int n    = (gg & 3) * 16 + (lane & 15);
            const int j    = vb * 64 + (gg >> 2) * 32 + (lane >> 4) * 8;
            const float* src = vt + (size_t)n * BT + j;
            float v[8];
            *(float4*)&v[0] = *(const float4*)src;
            *(float4*)&v[4] = *(const float4*)(src + 4);
            union { unsigned short u[8]; int4 i4; } pk;
            #pragma unroll
            for (int e = 0; e < 8; ++e) pk.u[e] = f2bf_rne(v[e]);
            *(int4*)(vf + ((size_t)(vb * 8 + gg) * 64 + lane) * 8) = pk.i4;
        }
    }
}

// ---------------------------------------------------------------------------
// Kernel 2: flash-style attention via MFMA. K/V staging now via
// global_load_lds from pre-converted fragment-ordered buffers — zero
// in-loop VALU conversion, no VGPR round-trip (same cure as qkv, round 13).
// MFMA/softmax math identical to round 8/13 -> bit-identical output.
// ---------------------------------------------------------------------------
__global__ __launch_bounds__(256) void attn_kernel(
    const float* __restrict__ q_ws,
    const short* __restrict__ kfh, const short* __restrict__ kfl,
    const short* __restrict__ vf, const int* __restrict__ maskp,
    float* __restrict__ part_O, float* __restrict__ part_ml, int BT)
{
    __shared__ __align__(16) short Kh[4096], Kl[4096];
    __shared__ __align__(16) short Vt[4096];
    __shared__ __align__(16) short Pl[4][16 * 72];

    const int tile  = blockIdx.x;
    const int chunk = blockIdx.y;
    const int r0 = tile * 64;
    const int tb = r0 / T_LEN;
    const int t0 = r0 - tb * T_LEN;
    const int mask = (*maskp != 0);
    const int n_max = mask ? (t0 + 64) : T_LEN;
    const int j0 = chunk * JCH;
    if (j0 >= n_max) return;
    const int hi_j = min(j0 + JCH, n_max);
    const int njt = (hi_j - j0 + 63) >> 6;

    const int tid  = threadIdx.x;
    const int w    = tid >> 6;
    const int lane = tid & 63;
    const int quad = lane >> 4;
    const int l15  = lane & 15;
    const int rw0  = t0 + 16 * w;
    const int rowa = r0 + 16 * w + quad * 4;

    bf16x8 qfh[2], qfl[2];
    {
        const float* qrow = q_ws + (size_t)(r0 + 16 * w + l15) * HS + quad * 8;
        #pragma unroll
        for (int kc = 0; kc < 2; ++kc) {
            float v[8];
            *(float4*)&v[0] = *(const float4*)(qrow + kc * 32);
            *(float4*)&v[4] = *(const float4*)(qrow + kc * 32 + 4);
            union { int4 i; bf16x8 b; } ch, cl;
            split8(v, ch.i, cl.i);
            qfh[kc] = ch.b;
            qfl[kc] = cl.b;
        }
    }

    f32x4 oacc[4];
    #pragma unroll
    for (int nt = 0; nt < 4; ++nt) oacc[nt] = (f32x4)(0.f);
    float m_r[4] = {-INFINITY, -INFINITY, -INFINITY, -INFINITY};
    float l_r[4] = {0.f, 0.f, 0.f, 0.f};

    for (int jt = 0; jt < njt; ++jt) {
        const int jbase = j0 + jt * 64;
        __syncthreads();
        // ---- async stage K (split) + V (bf16): 24 wave-uniform 1KB copies
        {
            const size_t kt0 = (size_t)(tb * 128) + (jbase >> 4); // global 16-j tile
            const size_t vb  = (size_t)(tb * 32) + (jbase >> 6);  // global 64-j tile
            #pragma unroll
            for (int ii = 0; ii < 6; ++ii) {
                const int g = w * 6 + ii;       // 0..23
                if (g < 8) {
                    const short* src = kfh + ((kt0 + (g >> 1)) * 2 + (g & 1)) * 512;
                    async_copy16(src + lane * 8, &Kh[g * 512]);
                } else if (g < 16) {
                    const int gg = g - 8;
                    const short* src = kfl + ((kt0 + (gg >> 1)) * 2 + (gg & 1)) * 512;
                    async_copy16(src + lane * 8, &Kl[gg * 512]);
                } else {
                    const int gg = g - 16;      // jc*4+nt
                    const short* src = vf + (vb * 8 + gg) * 512;
                    async_copy16(src + lane * 8, &Vt[gg * 512]);
                }
            }
        }
        __syncthreads();

        const bool active = (!mask) || (jbase <= rw0 + 15);
        if (active) {
            f32x4 sacc[4];
            #pragma unroll
            for (int jsub = 0; jsub < 4; ++jsub) {
                f32x4 s = (f32x4)(0.f);
                #pragma unroll
                for (int kc = 0; kc < 2; ++kc) {
                    const bf16x8 kh = *(const bf16x8*)&Kh[((jsub * 2 + kc) * 64 + lane) * 8];
                    const bf16x8 kl = *(const bf16x8*)&Kl[((jsub * 2 + kc) * 64 + lane) * 8];
                    s = __builtin_amdgcn_mfma_f32_16x16x32_bf16(qfh[kc], kh, s, 0, 0, 0);
                    s = __builtin_amdgcn_mfma_f32_16x16x32_bf16(qfh[kc], kl, s, 0, 0, 0);
                    s = __builtin_amdgcn_mfma_f32_16x16x32_bf16(qfl[kc], kh, s, 0, 0, 0);
                }
                sacc[jsub] = s;
            }
            float sval[4][4], rmax[4];
            #pragma unroll
            for (int r = 0; r < 4; ++r) rmax[r] = -INFINITY;
            #pragma unroll
            for (int jsub = 0; jsub < 4; ++jsub) {
                const int jg = jbase + jsub * 16 + l15;
                #pragma unroll
                for (int r = 0; r < 4; ++r) {
                    const int tg = rw0 + quad * 4 + r;
                    const float vv = (mask && (jg > tg)) ? -INFINITY : 8.0f * sacc[jsub][r];
                    sval[jsub][r] = vv;
                    rmax[r] = fmaxf(rmax[r], vv);
                }
            }
            #pragma unroll
            for (int d = 1; d < 16; d <<= 1)
                #pragma unroll
                for (int r = 0; r < 4; ++r)
                    rmax[r] = fmaxf(rmax[r], __shfl_xor(rmax[r], d));
            float alpha[4], msafe[4];
            #pragma unroll
            for (int r = 0; r < 4; ++r) {
                const float mn = fmaxf(m_r[r], rmax[r]);
                msafe[r] = (mn == -INFINITY) ? 0.f : mn;
                alpha[r] = __expf(m_r[r] - msafe[r]);
                m_r[r] = mn;
            }
            short* Pw = &Pl[w][0];
            float rsum[4] = {0.f, 0.f, 0.f, 0.f};
            #pragma unroll
            for (int jsub = 0; jsub < 4; ++jsub) {
                #pragma unroll
                for (int r = 0; r < 4; ++r) {
                    const float e = __expf(sval[jsub][r] - msafe[r]);
                    const unsigned short eb = f2bf_rne(e);
                    Pw[(quad * 4 + r) * 72 + jsub * 16 + l15] = (short)eb;
                    rsum[r] += bf2f(eb);
                }
            }
            #pragma unroll
            for (int d = 1; d < 16; d <<= 1)
                #pragma unroll
                for (int r = 0; r < 4; ++r)
                    rsum[r] += __shfl_xor(rsum[r], d);
            #pragma unroll
            for (int r = 0; r < 4; ++r)
                l_r[r] = l_r[r] * alpha[r] + rsum[r];
            #pragma unroll
            for (int nt = 0; nt < 4; ++nt)
                #pragma unroll
                for (int r = 0; r < 4; ++r)
                    oacc[nt][r] *= alpha[r];
            bf16x8 pf[2];
            #pragma unroll
            for (int jc = 0; jc < 2; ++jc)
                pf[jc] = *(const bf16x8*)&Pw[l15 * 72 + jc * 32 + quad * 8];
            #pragma unroll
            for (int nt = 0; nt < 4; ++nt) {
                #pragma unroll
                for (int jc = 0; jc < 2; ++jc) {
                    const bf16x8 vfr = *(const bf16x8*)&Vt[((jc * 4 + nt) * 64 + lane) * 8];
                    oacc[nt] = __builtin_amdgcn_mfma_f32_16x16x32_bf16(pf[jc], vfr, oacc[nt], 0, 0, 0);
                }
            }
        }
    }

    #pragma unroll
    for (int nt = 0; nt < 4; ++nt)
        #pragma unroll
        for (int r = 0; r < 4; ++r)
            part_O[((size_t)(rowa + r) * NCH + chunk) * HS + nt * 16 + l15] = oacc[nt][r];
    if (l15 == 0) {
        #pragma unroll
        for (int r = 0; r < 4; ++r) {
            float2 ml;
            ml.x = m_r[r];
            ml.y = l_r[r];
            *(float2*)(part_ml + ((size_t)(rowa + r) * NCH + chunk) * 2) = ml;
        }
    }
}

// ---------------------------------------------------------------------------
// Kernel 3: combine chunk partials — UNCHANGED (passing).
// ---------------------------------------------------------------------------
__global__ __launch_bounds__(256) void combine_kernel(
    const float* __restrict__ part_O, const float* __restrict__ part_ml,
    const int* __restrict__ maskp, float* __restrict__ out)
{
    const int f = blockIdx.x * 256 + threadIdx.x;
    const int row = f >> 6;
    const int d = f & 63;
    const int t = row & (T_LEN - 1);
    const int mask = (*maskp != 0);
    const int n = mask ? (t + 1) : T_LEN;
    const int nc = (n + JCH - 1) / JCH;

    const float2* mlp = (const float2*)(part_ml + (size_t)row * NCH * 2);
    float M = -INFINITY;
    for (int c = 0; c < nc; ++c) M = fmaxf(M, mlp[c].x);
    float L = 0.f, O = 0.f;
    for (int c = 0; c < nc; ++c) {
        const float2 ml = mlp[c];
        const float w = __expf(ml.x - M);
        L += ml.y * w;
        O = fmaf(part_O[((size_t)row * NCH + c) * HS + d], w, O);
    }
    out[(size_t)row * HS + d] = O / L;
}

// ---------------------------------------------------------------------------
extern "C" void kernel_launch(void* const* d_in, const int* in_sizes, int n_in,
                              void* d_out, int out_size, void* d_ws, size_t ws_size,
                              hipStream_t stream) {
    const float* x  = (const float*)d_in[0];
    const float* Wq = (const float*)d_in[1];
    const float* bq = (const float*)d_in[2];
    const float* Wk = (const float*)d_in[3];
    const float* bk = (const float*)d_in[4];
    const float* Wv = (const float*)d_in[5];
    const int* maskp = (const int*)d_in[6];

    const int BT = in_sizes[0] / D_MODEL;   // 8192

    // ws layout: floats q,k [BT*64], vt [64*BT], pO [BT*NCH*64], pml [BT*NCH*2];
    // shorts xh,xl [BT*1024], wh,wl [192*1024], kfh,kfl [BT*64], vf [BT*64].
    float* q   = (float*)d_ws;
    float* k   = q + (size_t)BT * HS;
    float* vt  = k + (size_t)BT * HS;
    float* pO  = vt + (size_t)BT * HS;
    float* pml = pO + (size_t)BT * NCH * HS;
    short* xh  = (short*)(pml + (size_t)BT * NCH * 2);
    short* xl  = xh + (size_t)BT * D_MODEL;
    short* wh  = xl + (size_t)BT * D_MODEL;
    short* wl  = wh + (size_t)192 * D_MODEL;
    short* kfh = wl + (size_t)192 * D_MODEL;
    short* kfl = kfh + (size_t)BT * HS;
    short* vf  = kfl + (size_t)BT * HS;

    prep_kernel<<<BT / 16 + 48, 256, 0, stream>>>(x, Wq, Wk, Wv, xh, xl, wh, wl, BT);
    dim3 qgrid(BT / 32, 3);
    qkv_kernel<<<qgrid, 256, 0, stream>>>(xh, xl, wh, wl, bq, bk, q, k, vt, BT);
    kvprep_kernel<<<BT / 32, 256, 0, stream>>>(k, vt, kfh, kfl, vf, BT);
    dim3 agrid(BT / 64, NCH);
    attn_kernel<<<agrid, 256, 0, stream>>>(q, kfh, kfl, vf, maskp, pO, pml, BT);
    combine_kernel<<<(BT * HS) / 256, 256, 0, stream>>>(pO, pml, maskp, (float*)d_out);
}

// Round 15
// 137.905 us; speedup vs baseline: 1.1252x; 1.0177x over previous
//
#include <hip/hip_runtime.h>
#include <hip/hip_bf16.h>

// AttentionHead: B=4, T=2048, C=1024, hs=64. All fp32 in/out.
#define D_MODEL 1024
#define HS 64
#define T_LEN 2048
#define JCH 256          // j-chunk width per attention block
#define NCH 8            // max chunks per row = T_LEN/JCH

typedef __attribute__((ext_vector_type(8))) short bf16x8;   // MFMA A/B frag
typedef __attribute__((ext_vector_type(4))) float f32x4;    // MFMA C/D frag

// split 8 floats into hi/lo bf16 (truncation split: residual exact)
__device__ inline void split8(const float* v, int4& hi, int4& lo) {
    union { unsigned short u[8]; int4 v4; } uh, ul;
    #pragma unroll
    for (int i = 0; i < 8; ++i) {
        const unsigned int b = __float_as_uint(v[i]);
        const unsigned short h = (unsigned short)(b >> 16);
        const float r = v[i] - __uint_as_float((unsigned int)h << 16);
        uh.u[i] = h;
        ul.u[i] = (unsigned short)(__float_as_uint(r) >> 16);
    }
    hi = uh.v4; lo = ul.v4;
}

// fp32 -> bf16 round-to-nearest-even (finite inputs only here)
__device__ inline unsigned short f2bf_rne(float f) {
    const unsigned int b = __float_as_uint(f);
    return (unsigned short)((b + 0x7FFFu + ((b >> 16) & 1u)) >> 16);
}
__device__ inline float bf2f(unsigned short h) {
    return __uint_as_float((unsigned int)h << 16);
}

// async 16B global -> LDS (direct-to-shared DMA). LDS dest is wave-uniform
// base; HW writes ldsbase + lane*16. gptr is per-lane.
__device__ inline void async_copy16(const short* g, short* l) {
    __builtin_amdgcn_global_load_lds(
        (const __attribute__((address_space(1))) void*)g,
        (__attribute__((address_space(3))) void*)l, 16, 0, 0);
}

// ---------------------------------------------------------------------------
// Kernel 0: prep — pre-split x and W into FRAGMENT-ORDERED bf16 hi/lo.
// (UNCHANGED from round 13/14 — passing.)
// ---------------------------------------------------------------------------
__global__ __launch_bounds__(256) void prep_kernel(
    const float* __restrict__ x,
    const float* __restrict__ Wq, const float* __restrict__ Wk,
    const float* __restrict__ Wv,
    short* __restrict__ xh, short* __restrict__ xl,
    short* __restrict__ wh, short* __restrict__ wl, int BT)
{
    __shared__ float tile[64][69];
    const int tid = threadIdx.x;
    const int bx  = blockIdx.x;
    const int nxb = BT >> 4;

    if (bx < nxb) {
        const int mtg = bx;
        #pragma unroll
        for (int i = 0; i < 8; ++i) {
            const int s    = tid + 256 * i;
            const int kc   = s >> 6;
            const int lane = s & 63;
            const float* src = x + (size_t)(mtg * 16 + (lane & 15)) * D_MODEL
                                 + kc * 32 + (lane >> 4) * 8;
            float v[8];
            *(float4*)&v[0] = *(const float4*)src;
            *(float4*)&v[4] = *(const float4*)(src + 4);
            int4 hi, lo;
            split8(v, hi, lo);
            const size_t off = ((size_t)(mtg * 32 + kc) * 64 + lane) * 8;
            *(int4*)(xh + off) = hi;
            *(int4*)(xl + off) = lo;
        }
    } else {
        const int wb = bx - nxb;
        const int kb = wb & 15;           // k-block 0..15
        const int m  = wb >> 4;           // matrix 0..2
        const float* W = (m == 0) ? Wq : (m == 1) ? Wk : Wv;
        #pragma unroll
        for (int it = 0; it < 4; ++it) {
            const int idx = tid + 256 * it;
            const int kr = idx >> 4, c4 = idx & 15;
            *(float4*)&tile[kr][4 * c4] =
                *(const float4*)(W + (size_t)(kb * 64 + kr) * HS + 4 * c4);
        }
        __syncthreads();
        #pragma unroll
        for (int i = 0; i < 2; ++i) {
            const int s    = tid + 256 * i;    // 0..511
            const int ntl  = s >> 7;           // 0..3
            const int kcl  = (s >> 6) & 1;
            const int lane = s & 63;
            const int n    = ntl * 16 + (lane & 15);
            const int krel = kcl * 32 + (lane >> 4) * 8;
            float v[8];
            #pragma unroll
            for (int e = 0; e < 8; ++e) v[e] = tile[krel + e][n];
            int4 hi, lo;
            split8(v, hi, lo);
            const size_t off =
                ((size_t)((m * 4 + ntl) * 32 + kb * 2 + kcl) * 64 + lane) * 8;
            *(int4*)(wh + off) = hi;
            *(int4*)(wl + off) = lo;
        }
    }
}

// ---------------------------------------------------------------------------
// Kernel 1: QKV projection (round-13 async-staging structure). Epilogue now
// writes q as fp32 AND k/v DIRECTLY in fragment-ordered bf16 (kfh/kfl split,
// vf RNE) — kvprep kernel fused away. Values bit-identical to the former
// k/vt fp32 round-trip (same fp32 acc+bias, same split/RNE).
// ---------------------------------------------------------------------------
__global__ __launch_bounds__(256) void qkv_kernel(
    const short* __restrict__ xh, const short* __restrict__ xl,
    const short* __restrict__ wh, const short* __restrict__ wl,
    const float* __restrict__ bq, const float* __restrict__ bk,
    float* __restrict__ q,
    short* __restrict__ kfh, short* __restrict__ kfl, short* __restrict__ vf,
    int BT)
{
    __shared__ __align__(16) short A_lds[8 * 512];
    __shared__ __align__(16) short B_lds[16 * 512];

    const int tid  = threadIdx.x;
    const int r0   = blockIdx.x * 32;
    const int nb   = blockIdx.y;
    const int wave = tid >> 6;
    const int lane = tid & 63;
    const int mt_w = wave >> 1;
    const int nt0  = (wave & 1) * 2;

    f32x4 acc0 = (f32x4)(0.f);
    f32x4 acc1 = (f32x4)(0.f);

    const size_t mtg0 = (size_t)(r0 >> 4);
    const size_t ntg0 = (size_t)(nb * 4);

    for (int k0 = 0; k0 < D_MODEL; k0 += 64) {
        const int kc0 = k0 >> 5;
        __syncthreads();
        #pragma unroll
        for (int ii = 0; ii < 6; ++ii) {
            const int g = wave * 6 + ii;
            if (g < 8) {
                const int mt = g >> 2, kcl = (g >> 1) & 1, p = g & 1;
                const short* base = p ? xl : xh;
                const short* gsrc = base + ((mtg0 + mt) * 32 + kc0 + kcl) * 512;
                async_copy16(gsrc + lane * 8, &A_lds[g * 512]);
            } else {
                const int gb = g - 8;
                const int nt = gb >> 2, kcl = (gb >> 1) & 1, p = gb & 1;
                const short* base = p ? wl : wh;
                const short* gsrc = base + ((ntg0 + nt) * 32 + kc0 + kcl) * 512;
                async_copy16(gsrc + lane * 8, &B_lds[gb * 512]);
            }
        }
        __syncthreads();
        #pragma unroll
        for (int kcl = 0; kcl < 2; ++kcl) {
            const bf16x8 afh = *(const bf16x8*)&A_lds[(mt_w * 4 + kcl * 2 + 0) * 512 + lane * 8];
            const bf16x8 afl = *(const bf16x8*)&A_lds[(mt_w * 4 + kcl * 2 + 1) * 512 + lane * 8];
            {
                const bf16x8 bfh = *(const bf16x8*)&B_lds[(nt0 * 4 + kcl * 2 + 0) * 512 + lane * 8];
                const bf16x8 bfl = *(const bf16x8*)&B_lds[(nt0 * 4 + kcl * 2 + 1) * 512 + lane * 8];
                acc0 = __builtin_amdgcn_mfma_f32_16x16x32_bf16(afh, bfh, acc0, 0, 0, 0);
                acc0 = __builtin_amdgcn_mfma_f32_16x16x32_bf16(afh, bfl, acc0, 0, 0, 0);
                acc0 = __builtin_amdgcn_mfma_f32_16x16x32_bf16(afl, bfh, acc0, 0, 0, 0);
            }
            {
                const bf16x8 bfh = *(const bf16x8*)&B_lds[((nt0 + 1) * 4 + kcl * 2 + 0) * 512 + lane * 8];
                const bf16x8 bfl = *(const bf16x8*)&B_lds[((nt0 + 1) * 4 + kcl * 2 + 1) * 512 + lane * 8];
                acc1 = __builtin_amdgcn_mfma_f32_16x16x32_bf16(afh, bfh, acc1, 0, 0, 0);
                acc1 = __builtin_amdgcn_mfma_f32_16x16x32_bf16(afh, bfl, acc1, 0, 0, 0);
                acc1 = __builtin_amdgcn_mfma_f32_16x16x32_bf16(afl, bfh, acc1, 0, 0, 0);
            }
        }
    }

    // ---- epilogue: C/D layout col=lane&15, row=(lane>>4)*4+reg
    const int rowb = r0 + mt_w * 16 + (lane >> 4) * 4;
    #pragma unroll
    for (int j = 0; j < 2; ++j) {
        const f32x4 a = (j == 0) ? acc0 : acc1;
        const int c = nb * 64 + (nt0 + j) * 16 + (lane & 15);
        if (c < 64) {
            const float bias = bq[c];
            #pragma unroll
            for (int r = 0; r < 4; ++r)
                q[(size_t)(rowb + r) * HS + c] = a[r] + bias;
        } else if (c < 128) {
            // k -> fragment-ordered split bf16 (kfh/kfl)
            const int ck    = c - 64;
            const float bias = bk[ck];
            const int ktile = rowb >> 4;
            const int kc2   = ck >> 5;
            const int quadd = (ck & 31) >> 3;
            const int e     = ck & 7;
            #pragma unroll
            for (int r = 0; r < 4; ++r) {
                const float val = a[r] + bias;
                const unsigned int b = __float_as_uint(val);
                const unsigned short h = (unsigned short)(b >> 16);
                const float res = val - __uint_as_float((unsigned int)h << 16);
                const unsigned short l16 = (unsigned short)(__float_as_uint(res) >> 16);
                const int laned = ((rowb + r) & 15) | (quadd << 4);
                const size_t off = ((size_t)((ktile * 2 + kc2) * 64 + laned)) * 8 + e;
                kfh[off] = (short)h;
                kfl[off] = (short)l16;
            }
        } else {
            // v -> fragment-ordered RNE bf16 (vf); 4 consecutive e -> 8B store
            const int cv    = c - 128;
            const int vb    = rowb >> 6;
            const int jc2   = (rowb & 63) >> 5;
            const int quadd = (rowb & 31) >> 3;
            const int gg    = jc2 * 4 + (cv >> 4);
            const int laned = (cv & 15) | (quadd << 4);
            const size_t base = ((size_t)((vb * 8 + gg) * 64 + laned)) * 8 + (rowb & 7);
            short4 pk;
            pk.x = (short)f2bf_rne(a[0]);
            pk.y = (short)f2bf_rne(a[1]);
            pk.z = (short)f2bf_rne(a[2]);
            pk.w = (short)f2bf_rne(a[3]);
            *(short4*)(vf + base) = pk;
        }
    }
}

// ---------------------------------------------------------------------------
// Kernel 2: flash-style attention via MFMA (round-14 async staging).
// JCH 256 -> live causal blocks ~576 (2.25/CU, was 1.25) for latency hiding.
// ---------------------------------------------------------------------------
__global__ __launch_bounds__(256) void attn_kernel(
    const float* __restrict__ q_ws,
    const short* __restrict__ kfh, const short* __restrict__ kfl,
    const short* __restrict__ vf, const int* __restrict__ maskp,
    float* __restrict__ part_O, float* __restrict__ part_ml, int BT)
{
    __shared__ __align__(16) short Kh[4096], Kl[4096];
    __shared__ __align__(16) short Vt[4096];
    __shared__ __align__(16) short Pl[4][16 * 72];

    const int tile  = blockIdx.x;
    const int chunk = blockIdx.y;
    const int r0 = tile * 64;
    const int tb = r0 / T_LEN;
    const int t0 = r0 - tb * T_LEN;
    const int mask = (*maskp != 0);
    const int n_max = mask ? (t0 + 64) : T_LEN;
    const int j0 = chunk * JCH;
    if (j0 >= n_max) return;
    const int hi_j = min(j0 + JCH, n_max);
    const int njt = (hi_j - j0 + 63) >> 6;

    const int tid  = threadIdx.x;
    const int w    = tid >> 6;
    const int lane = tid & 63;
    const int quad = lane >> 4;
    const int l15  = lane & 15;
    const int rw0  = t0 + 16 * w;
    const int rowa = r0 + 16 * w + quad * 4;

    bf16x8 qfh[2], qfl[2];
    {
        const float* qrow = q_ws + (size_t)(r0 + 16 * w + l15) * HS + quad * 8;
        #pragma unroll
        for (int kc = 0; kc < 2; ++kc) {
            float v[8];
            *(float4*)&v[0] = *(const float4*)(qrow + kc * 32);
            *(float4*)&v[4] = *(const float4*)(qrow + kc * 32 + 4);
            union { int4 i; bf16x8 b; } ch, cl;
            split8(v, ch.i, cl.i);
            qfh[kc] = ch.b;
            qfl[kc] = cl.b;
        }
    }

    f32x4 oacc[4];
    #pragma unroll
    for (int nt = 0; nt < 4; ++nt) oacc[nt] = (f32x4)(0.f);
    float m_r[4] = {-INFINITY, -INFINITY, -INFINITY, -INFINITY};
    float l_r[4] = {0.f, 0.f, 0.f, 0.f};

    for (int jt = 0; jt < njt; ++jt) {
        const int jbase = j0 + jt * 64;
        __syncthreads();
        {
            const size_t kt0 = (size_t)(tb * 128) + (jbase >> 4);
            const size_t vb  = (size_t)(tb * 32) + (jbase >> 6);
            #pragma unroll
            for (int ii = 0; ii < 6; ++ii) {
                const int g = w * 6 + ii;       // 0..23
                if (g < 8) {
                    const short* src = kfh + ((kt0 + (g >> 1)) * 2 + (g & 1)) * 512;
                    async_copy16(src + lane * 8, &Kh[g * 512]);
                } else if (g < 16) {
                    const int gg = g - 8;
                    const short* src = kfl + ((kt0 + (gg >> 1)) * 2 + (gg & 1)) * 512;
                    async_copy16(src + lane * 8, &Kl[gg * 512]);
                } else {
                    const int gg = g - 16;
                    const short* src = vf + (vb * 8 + gg) * 512;
                    async_copy16(src + lane * 8, &Vt[gg * 512]);
                }
            }
        }
        __syncthreads();

        const bool active = (!mask) || (jbase <= rw0 + 15);
        if (active) {
            f32x4 sacc[4];
            #pragma unroll
            for (int jsub = 0; jsub < 4; ++jsub) {
                f32x4 s = (f32x4)(0.f);
                #pragma unroll
                for (int kc = 0; kc < 2; ++kc) {
                    const bf16x8 kh = *(const bf16x8*)&Kh[((jsub * 2 + kc) * 64 + lane) * 8];
                    const bf16x8 kl = *(const bf16x8*)&Kl[((jsub * 2 + kc) * 64 + lane) * 8];
                    s = __builtin_amdgcn_mfma_f32_16x16x32_bf16(qfh[kc], kh, s, 0, 0, 0);
                    s = __builtin_amdgcn_mfma_f32_16x16x32_bf16(qfh[kc], kl, s, 0, 0, 0);
                    s = __builtin_amdgcn_mfma_f32_16x16x32_bf16(qfl[kc], kh, s, 0, 0, 0);
                }
                sacc[jsub] = s;
            }
            float sval[4][4], rmax[4];
            #pragma unroll
            for (int r = 0; r < 4; ++r) rmax[r] = -INFINITY;
            #pragma unroll
            for (int jsub = 0; jsub < 4; ++jsub) {
                const int jg = jbase + jsub * 16 + l15;
                #pragma unroll
                for (int r = 0; r < 4; ++r) {
                    const int tg = rw0 + quad * 4 + r;
                    const float vv = (mask && (jg > tg)) ? -INFINITY : 8.0f * sacc[jsub][r];
                    sval[jsub][r] = vv;
                    rmax[r] = fmaxf(rmax[r], vv);
                }
            }
            #pragma unroll
            for (int d = 1; d < 16; d <<= 1)
                #pragma unroll
                for (int r = 0; r < 4; ++r)
                    rmax[r] = fmaxf(rmax[r], __shfl_xor(rmax[r], d));
            float alpha[4], msafe[4];
            #pragma unroll
            for (int r = 0; r < 4; ++r) {
                const float mn = fmaxf(m_r[r], rmax[r]);
                msafe[r] = (mn == -INFINITY) ? 0.f : mn;
                alpha[r] = __expf(m_r[r] - msafe[r]);
                m_r[r] = mn;
            }
            short* Pw = &Pl[w][0];
            float rsum[4] = {0.f, 0.f, 0.f, 0.f};
            #pragma unroll
            for (int jsub = 0; jsub < 4; ++jsub) {
                #pragma unroll
                for (int r = 0; r < 4; ++r) {
                    const float e = __expf(sval[jsub][r] - msafe[r]);
                    const unsigned short eb = f2bf_rne(e);
                    Pw[(quad * 4 + r) * 72 + jsub * 16 + l15] = (short)eb;
                    rsum[r] += bf2f(eb);
                }
            }
            #pragma unroll
            for (int d = 1; d < 16; d <<= 1)
                #pragma unroll
                for (int r = 0; r < 4; ++r)
                    rsum[r] += __shfl_xor(rsum[r], d);
            #pragma unroll
            for (int r = 0; r < 4; ++r)
                l_r[r] = l_r[r] * alpha[r] + rsum[r];
            #pragma unroll
            for (int nt = 0; nt < 4; ++nt)
                #pragma unroll
                for (int r = 0; r < 4; ++r)
                    oacc[nt][r] *= alpha[r];
            bf16x8 pf[2];
            #pragma unroll
            for (int jc = 0; jc < 2; ++jc)
                pf[jc] = *(const bf16x8*)&Pw[l15 * 72 + jc * 32 + quad * 8];
            #pragma unroll
            for (int nt = 0; nt < 4; ++nt) {
                #pragma unroll
                for (int jc = 0; jc < 2; ++jc) {
                    const bf16x8 vfr = *(const bf16x8*)&Vt[((jc * 4 + nt) * 64 + lane) * 8];
                    oacc[nt] = __builtin_amdgcn_mfma_f32_16x16x32_bf16(pf[jc], vfr, oacc[nt], 0, 0, 0);
                }
            }
        }
    }

    #pragma unroll
    for (int nt = 0; nt < 4; ++nt)
        #pragma unroll
        for (int r = 0; r < 4; ++r)
            part_O[((size_t)(rowa + r) * NCH + chunk) * HS + nt * 16 + l15] = oacc[nt][r];
    if (l15 == 0) {
        #pragma unroll
        for (int r = 0; r < 4; ++r) {
            float2 ml;
            ml.x = m_r[r];
            ml.y = l_r[r];
            *(float2*)(part_ml + ((size_t)(rowa + r) * NCH + chunk) * 2) = ml;
        }
    }
}

// ---------------------------------------------------------------------------
// Kernel 3: combine chunk partials — two-pass, no runtime-indexed arrays.
// ---------------------------------------------------------------------------
__global__ __launch_bounds__(256) void combine_kernel(
    const float* __restrict__ part_O, const float* __restrict__ part_ml,
    const int* __restrict__ maskp, float* __restrict__ out)
{
    const int f = blockIdx.x * 256 + threadIdx.x;
    const int row = f >> 6;
    const int d = f & 63;
    const int t = row & (T_LEN - 1);
    const int mask = (*maskp != 0);
    const int n = mask ? (t + 1) : T_LEN;
    const int nc = (n + JCH - 1) / JCH;

    const float2* mlp = (const float2*)(part_ml + (size_t)row * NCH * 2);
    float M = -INFINITY;
    for (int c = 0; c < nc; ++c) M = fmaxf(M, mlp[c].x);
    float L = 0.f, O = 0.f;
    for (int c = 0; c < nc; ++c) {
        const float2 ml = mlp[c];
        const float w = __expf(ml.x - M);
        L += ml.y * w;
        O = fmaf(part_O[((size_t)row * NCH + c) * HS + d], w, O);
    }
    out[(size_t)row * HS + d] = O / L;
}

// ---------------------------------------------------------------------------
extern "C" void kernel_launch(void* const* d_in, const int* in_sizes, int n_in,
                              void* d_out, int out_size, void* d_ws, size_t ws_size,
                              hipStream_t stream) {
    const float* x  = (const float*)d_in[0];
    const float* Wq = (const float*)d_in[1];
    const float* bq = (const float*)d_in[2];
    const float* Wk = (const float*)d_in[3];
    const float* bk = (const float*)d_in[4];
    const float* Wv = (const float*)d_in[5];
    const int* maskp = (const int*)d_in[6];

    const int BT = in_sizes[0] / D_MODEL;   // 8192

    // ws layout: floats q [BT*64], pO [BT*NCH*64], pml [BT*NCH*2];
    // shorts xh,xl [BT*1024], wh,wl [192*1024], kfh,kfl [BT*64], vf [BT*64].
    float* q   = (float*)d_ws;
    float* pO  = q + (size_t)BT * HS;
    float* pml = pO + (size_t)BT * NCH * HS;
    short* xh  = (short*)(pml + (size_t)BT * NCH * 2);
    short* xl  = xh + (size_t)BT * D_MODEL;
    short* wh  = xl + (size_t)BT * D_MODEL;
    short* wl  = wh + (size_t)192 * D_MODEL;
    short* kfh = wl + (size_t)192 * D_MODEL;
    short* kfl = kfh + (size_t)BT * HS;
    short* vf  = kfl + (size_t)BT * HS;

    prep_kernel<<<BT / 16 + 48, 256, 0, stream>>>(x, Wq, Wk, Wv, xh, xl, wh, wl, BT);
    dim3 qgrid(BT / 32, 3);
    qkv_kernel<<<qgrid, 256, 0, stream>>>(xh, xl, wh, wl, bq, bk, q, kfh, kfl, vf, BT);
    dim3 agrid(BT / 64, NCH);
    attn_kernel<<<agrid, 256, 0, stream>>>(q, kfh, kfl, vf, maskp, pO, pml, BT);
    combine_kernel<<<(BT * HS) / 256, 256, 0, stream>>>(pO, pml, maskp, (float*)d_out);
}